// Round 1
// 141.797 us; speedup vs baseline: 1.0423x; 1.0423x over previous
//
#include <hip/hip_runtime.h>
#include <hip/hip_bf16.h>

#define BB 4
#define TT 2048
#define DIM 512
#define NH 8
#define HD 64
#define NROW (BB*TT)   // 8192
#define BH (BB*NH)     // 32

typedef unsigned short u16;
typedef unsigned int u32;
typedef __attribute__((ext_vector_type(8))) short bf16x8;   // 8 bf16 = 4 VGPRs
typedef __attribute__((ext_vector_type(8))) unsigned short u16x8;
typedef __attribute__((ext_vector_type(4))) float f32x4;
typedef __attribute__((ext_vector_type(4))) unsigned short u16x4;

static __device__ __forceinline__ float bf2f(u16 u) {
    return __uint_as_float(((u32)u) << 16);
}
static __device__ __forceinline__ u16 f2bf(float f) {
    u32 u = __float_as_uint(f);
    u32 r = (u + 0x7FFFu + ((u >> 16) & 1u)) >> 16;
    return (u16)r;
}
// packed f32x2 -> bf16x2 (v_cvt_pk_bf16_f32 on gfx950)
static __device__ __forceinline__ u32 cvtpk(float a, float b) {
    union { __hip_bfloat162 h2; u32 u; } cv;
    cv.h2 = __float22bfloat162_rn(make_float2(a, b));
    return cv.u;
}
// async global -> LDS, 16B per lane. LDS dest = wave-uniform base + lane*16.
static __device__ __forceinline__ void gll16(const u16* g, u16* l) {
    __builtin_amdgcn_global_load_lds(
        (const __attribute__((address_space(1))) unsigned int*)g,
        (__attribute__((address_space(3))) unsigned int*)l,
        16, 0, 0);
}

// ---------------- prep: fused convert_x (blocks 0..255) + W transposes
__global__ __launch_bounds__(256) void prep_kernel(
    const float* __restrict__ x, u16* __restrict__ x16, u32* __restrict__ bmaxsq,
    const float* __restrict__ Wqkv, u16* __restrict__ Wtq,
    const float* __restrict__ Wproj, u16* __restrict__ Wtp)
{
    const int bid = blockIdx.x;
    const int tid = threadIdx.x;
    __shared__ u16 t[32][33];
    __shared__ float red[4];

    if (bid < 256) {
        const int row = bid * 32 + (tid >> 3);
        const int b = (bid * 32) >> 11;
        const float* xr = x   + (size_t)row * DIM + (tid & 7) * 64;
        u16*        xo  = x16 + (size_t)row * DIM + (tid & 7) * 64;
        float s = 0.0f;
        #pragma unroll
        for (int j = 0; j < 8; ++j) {
            float4 a = *(const float4*)(xr + j*8);
            float4 c = *(const float4*)(xr + j*8 + 4);
            s += a.x*a.x + a.y*a.y + a.z*a.z + a.w*a.w;
            s += c.x*c.x + c.y*c.y + c.z*c.z + c.w*c.w;
            u16x8 pk;
            pk[0]=f2bf(a.x); pk[1]=f2bf(a.y); pk[2]=f2bf(a.z); pk[3]=f2bf(a.w);
            pk[4]=f2bf(c.x); pk[5]=f2bf(c.y); pk[6]=f2bf(c.z); pk[7]=f2bf(c.w);
            *(u16x8*)(xo + j*8) = pk;
        }
        #pragma unroll
        for (int off = 1; off < 8; off <<= 1) s += __shfl_xor(s, off, 64);
        float m = s;
        #pragma unroll
        for (int off = 8; off < 64; off <<= 1) m = fmaxf(m, __shfl_xor(m, off, 64));
        if ((tid & 63) == 0) red[tid >> 6] = m;
        __syncthreads();
        if (tid == 0) {
            float mx = fmaxf(fmaxf(red[0], red[1]), fmaxf(red[2], red[3]));
            atomicMax(&bmaxsq[b], __float_as_uint(mx));
        }
    } else {
        const float* in; u16* outp; int K, N, tb;
        if (bid < 768) { in = Wqkv; outp = Wtq; K = 512; N = 1024; tb = bid - 256; }
        else           { in = Wproj; outp = Wtp; K = 512; N = 512;  tb = bid - 768; }
        const int ntiles = N >> 5;
        const int bx = tb % ntiles, by = tb / ntiles;
        const int n0 = bx * 32, k0 = by * 32;
        const int tx = tid & 31, ty = tid >> 5;
        #pragma unroll
        for (int i = 0; i < 32; i += 8)
            t[ty + i][tx] = f2bf(in[(size_t)(k0 + ty + i) * N + n0 + tx]);
        __syncthreads();
        #pragma unroll
        for (int i = 0; i < 32; i += 8)
            outp[(size_t)(n0 + ty + i) * K + k0 + tx] = t[tx][ty + i];
    }
}

// ---------------- MFMA GEMM: qkv = x16 @ Wqkv (via Wt [1024][512] bf16)
#define LDG 72
__global__ __launch_bounds__(256) void qkv_mfma(
    const u16* __restrict__ x16, const u16* __restrict__ Wt,
    u16* __restrict__ q16, u16* __restrict__ vt16)
{
    const int tid = threadIdx.x, lane = tid & 63, w = tid >> 6;
    const int li = lane & 15, quad = lane >> 4;
    const int mb = blockIdx.x >> 3, nb = blockIdx.x & 7;   // 64 x 8
    const int row0 = mb * 128, n0 = nb * 128;
    const int b = row0 >> 11;
    const int wm = w >> 1, wn = w & 1;

    __shared__ __align__(16) u16 as[128 * LDG];
    __shared__ __align__(16) u16 bs[128 * LDG];

    f32x4 acc[4][4];
    #pragma unroll
    for (int mi = 0; mi < 4; ++mi)
        #pragma unroll
        for (int ni = 0; ni < 4; ++ni) acc[mi][ni] = f32x4{0.f,0.f,0.f,0.f};

    for (int k0 = 0; k0 < DIM; k0 += 64) {
        __syncthreads();
        #pragma unroll
        for (int it = 0; it < 4; ++it) {
            int id = it * 256 + tid;
            int r = id >> 3, c = id & 7;
            *(bf16x8*)&as[r*LDG + c*8] =
                *(const bf16x8*)(x16 + (size_t)(row0 + r)*DIM + k0 + c*8);
            *(bf16x8*)&bs[r*LDG + c*8] =
                *(const bf16x8*)(Wt  + (size_t)(n0  + r)*DIM + k0 + c*8);
        }
        __syncthreads();

        bf16x8 af[4][2], bfr[4][2];
        #pragma unroll
        for (int mi = 0; mi < 4; ++mi) {
            const u16* p = &as[(wm*64 + mi*16 + li)*LDG + quad*8];
            af[mi][0] = *(const bf16x8*)p;
            af[mi][1] = *(const bf16x8*)(p + 32);
        }
        #pragma unroll
        for (int ni = 0; ni < 4; ++ni) {
            const u16* p = &bs[(wn*64 + ni*16 + li)*LDG + quad*8];
            bfr[ni][0] = *(const bf16x8*)p;
            bfr[ni][1] = *(const bf16x8*)(p + 32);
        }
        #pragma unroll
        for (int mi = 0; mi < 4; ++mi)
            #pragma unroll
            for (int ni = 0; ni < 4; ++ni) {
                acc[mi][ni] = __builtin_amdgcn_mfma_f32_16x16x32_bf16(
                    af[mi][0], bfr[ni][0], acc[mi][ni], 0, 0, 0);
                acc[mi][ni] = __builtin_amdgcn_mfma_f32_16x16x32_bf16(
                    af[mi][1], bfr[ni][1], acc[mi][ni], 0, 0, 0);
            }
    }

    const int h = li & 7;
    const bool isv = ((li >> 3) & 1) != 0;
    #pragma unroll
    for (int ni = 0; ni < 4; ++ni) {
        int col0 = n0 + wn*64 + ni*16;
        int d = col0 >> 4;
        #pragma unroll
        for (int mi = 0; mi < 4; ++mi) {
            int t0 = (row0 & (TT-1)) + wm*64 + mi*16 + quad*4;
            if (!isv) {
                u16* dst = q16 + ((size_t)(b*NH + h)*TT + t0)*HD + d;
                #pragma unroll
                for (int r = 0; r < 4; ++r)
                    dst[(size_t)r * HD] = f2bf(acc[mi][ni][r]);
            } else {
                u16x4 pk;
                pk.x = f2bf(acc[mi][ni][0]); pk.y = f2bf(acc[mi][ni][1]);
                pk.z = f2bf(acc[mi][ni][2]); pk.w = f2bf(acc[mi][ni][3]);
                *(u16x4*)(vt16 + ((size_t)(b*NH + h)*HD + d)*TT + t0) = pk;
            }
        }
    }
}

// ---------------- MFMA GEMM: out(f32) = ao16 @ Wproj + bias(f32)
__global__ __launch_bounds__(256) void proj_mfma(
    const u16* __restrict__ ao16, const u16* __restrict__ Wt,
    const float* __restrict__ bp, float* __restrict__ out)
{
    const int tid = threadIdx.x, lane = tid & 63, w = tid >> 6;
    const int li = lane & 15, quad = lane >> 4;
    const int mb = blockIdx.x >> 2, nb = blockIdx.x & 3;   // 64 x 4
    const int row0 = mb * 128, n0 = nb * 128;
    const int wm = w >> 1, wn = w & 1;

    __shared__ __align__(16) u16 as[128 * LDG];
    __shared__ __align__(16) u16 bs[128 * LDG];

    f32x4 acc[4][4];
    #pragma unroll
    for (int mi = 0; mi < 4; ++mi)
        #pragma unroll
        for (int ni = 0; ni < 4; ++ni) acc[mi][ni] = f32x4{0.f,0.f,0.f,0.f};

    for (int k0 = 0; k0 < DIM; k0 += 64) {
        __syncthreads();
        #pragma unroll
        for (int it = 0; it < 4; ++it) {
            int id = it * 256 + tid;
            int r = id >> 3, c = id & 7;
            *(bf16x8*)&as[r*LDG + c*8] =
                *(const bf16x8*)(ao16 + (size_t)(row0 + r)*DIM + k0 + c*8);
            *(bf16x8*)&bs[r*LDG + c*8] =
                *(const bf16x8*)(Wt   + (size_t)(n0  + r)*DIM + k0 + c*8);
        }
        __syncthreads();

        bf16x8 af[4][2], bfr[4][2];
        #pragma unroll
        for (int mi = 0; mi < 4; ++mi) {
            const u16* p = &as[(wm*64 + mi*16 + li)*LDG + quad*8];
            af[mi][0] = *(const bf16x8*)p;
            af[mi][1] = *(const bf16x8*)(p + 32);
        }
        #pragma unroll
        for (int ni = 0; ni < 4; ++ni) {
            const u16* p = &bs[(wn*64 + ni*16 + li)*LDG + quad*8];
            bfr[ni][0] = *(const bf16x8*)p;
            bfr[ni][1] = *(const bf16x8*)(p + 32);
        }
        #pragma unroll
        for (int mi = 0; mi < 4; ++mi)
            #pragma unroll
            for (int ni = 0; ni < 4; ++ni) {
                acc[mi][ni] = __builtin_amdgcn_mfma_f32_16x16x32_bf16(
                    af[mi][0], bfr[ni][0], acc[mi][ni], 0, 0, 0);
                acc[mi][ni] = __builtin_amdgcn_mfma_f32_16x16x32_bf16(
                    af[mi][1], bfr[ni][1], acc[mi][ni], 0, 0, 0);
            }
    }

    #pragma unroll
    for (int ni = 0; ni < 4; ++ni) {
        int col = n0 + wn*64 + ni*16 + li;
        float bias = bp[col];
        #pragma unroll
        for (int mi = 0; mi < 4; ++mi) {
            int r0 = row0 + wm*64 + mi*16 + quad*4;
            #pragma unroll
            for (int r = 0; r < 4; ++r)
                out[(size_t)(r0 + r)*DIM + col] = acc[mi][ni][r] + bias;
        }
    }
}

// ---------------- qsq: qsq[b,h,t] = sum_d q^2 ; asq[b,h] via 1 atomic/block
__global__ __launch_bounds__(256) void qsq_kernel(
    const u16* __restrict__ q16, float* __restrict__ qsq, float* __restrict__ asq)
{
    const int tid = threadIdx.x;
    const int bh = blockIdx.x >> 3;
    const int r0 = (blockIdx.x & 7) * 256;
    const u16* qb = q16 + ((size_t)bh * TT + r0) * HD;

    float tot = 0.0f;
    #pragma unroll
    for (int i = 0; i < 8; ++i) {
        int row = i * 32 + (tid >> 3);
        u16x8 v = *(const u16x8*)(qb + (size_t)row * HD + (tid & 7) * 8);
        float s = 0.0f;
        #pragma unroll
        for (int j = 0; j < 8; ++j) { float f = bf2f(v[j]); s += f * f; }
        tot += s;
        #pragma unroll
        for (int off = 1; off < 8; off <<= 1) s += __shfl_xor(s, off, 64);
        if ((tid & 7) == 0) qsq[(size_t)bh * TT + r0 + row] = s;
    }
    __shared__ float red[4];
    #pragma unroll
    for (int off = 32; off > 0; off >>= 1) tot += __shfl_down(tot, off, 64);
    if ((tid & 63) == 0) red[tid >> 6] = tot;
    __syncthreads();
    if (tid == 0) atomicAdd(&asq[bh], red[0] + red[1] + red[2] + red[3]);
}

// ---------------- attention v7:
// 4 waves x 32 q-rows (was 8 x 16): halves per-FLOP K/V LDS reads.
// K/V tiles [64][64] bf16, XOR-swizzled (slot ^= row&7), staged by
// global_load_lds with pre-swizzled global source cols (linear LDS dest).
// 2-phase DMA double-buffer: issue next-tile gll, compute, vmcnt(0)+barrier.
#define LDP 72
__global__ __launch_bounds__(256) void attn_kernel(
    const u16* __restrict__ q16, const u16* __restrict__ vt16,
    const float* __restrict__ qsq, const float* __restrict__ asq,
    const u32* __restrict__ bmaxsq, u16* __restrict__ ao16)
{
    const int tid = threadIdx.x;
    const int lane = tid & 63, w = tid >> 6;          // 4 waves
    const int li = lane & 15, quad = lane >> 4;
    const int l7 = lane & 7;
    const int bh = blockIdx.x >> 4;                   // 32
    const int qtile = blockIdx.x & 15;                // 16 tiles x 128 q-rows
    const int b = bh >> 3, h = bh & 7;

    __shared__ __align__(16) u16 ks0[64 * 64];        // K tile buf0 (swizzled)
    __shared__ __align__(16) u16 ks1[64 * 64];
    __shared__ __align__(16) u16 vt0[64 * 64];        // V^T tile buf0 (swizzled)
    __shared__ __align__(16) u16 vt1[64 * 64];
    __shared__ __align__(16) u16 ps[4][32 * LDP];     // per-wave P [t=32][s=64]

    const u16* qg = q16  + (size_t)bh * TT * HD;      // [t][d]
    const u16* vg = vt16 + (size_t)bh * HD * TT;      // [d][t]
    const float* qsqg = qsq + (size_t)bh * TT;

    float cf;   // 100 * log2(e) / (a * bmax + eps)
    {
        float a  = sqrtf(asq[bh]);
        float bm = sqrtf(__uint_as_float(bmaxsq[b]));
        cf = (100.0f * 1.44269504089f) / (a * bm + 1e-10f);
    }
    const float c2 = 2.0f * cf;

    // Q fragments for 2 sub-tiles of 16 rows each (t-col = li)
    const int qt0w = qtile * 128 + w * 32;
    bf16x8 a0[2], a1[2];
    float sqt[2];
    #pragma unroll
    for (int qi = 0; qi < 2; ++qi) {
        const u16* qr = qg + (size_t)(qt0w + qi*16 + li) * HD + quad * 8;
        a0[qi] = *(const bf16x8*)qr;
        a1[qi] = *(const bf16x8*)(qr + 32);
        sqt[qi] = cf * qsqg[qt0w + qi*16 + li];
    }

    // swizzled per-lane frag read offsets (elements); rows have 64 elems.
    // slot0 = quad, slot1 = quad+4, both XOR'd with (row&7)=(li&7)
    const int koff0 = li * 64 + ((quad ^ l7) << 3);
    const int koff1 = li * 64 + (((quad + 4) ^ l7) << 3);

    // staging: 256 threads, each 2x16B K-chunks + 2x16B V-chunks per tile.
    // LDS dest is linear (chunk id = tid, tid+256); global source col is
    // inverse-swizzled so LDS[r][s] = T[r][s ^ (r&7)].
    const int rk = tid >> 3;
    const int ck = (tid & 7) ^ (rk & 7);
    const u16* kstg = qg + (size_t)rk * HD + ck * 8;  // + t*64*HD per tile
    const u16* vstg = vg + (size_t)rk * TT + ck * 8;  // + t*64 per tile
    const int lb0 = w * 512;                          // wave-uniform LDS base
    const int lb1 = 2048 + w * 512;

    u16* psw = &ps[w][0];
    float ssum[2] = {0.0f, 0.0f};
    f32x4 oacc[2][4];
    #pragma unroll
    for (int qi = 0; qi < 2; ++qi)
        #pragma unroll
        for (int dj = 0; dj < 4; ++dj) oacc[qi][dj] = f32x4{0.f, 0.f, 0.f, 0.f};

    auto stage = [&](u16* ksb, u16* vtb, int t) {
        const u16* kp = kstg + (size_t)t * 64 * HD;
        const u16* vp = vstg + t * 64;
        gll16(kp,                 ksb + lb0);
        gll16(kp + 32 * HD,       ksb + lb1);
        gll16(vp,                 vtb + lb0);
        gll16(vp + (size_t)32*TT, vtb + lb1);
    };

    // per-tile compute against a fixed buffer pair (offsets fold to imm)
    auto tile_compute = [&](const u16* __restrict__ ksb,
                            const u16* __restrict__ vtb, int s0) {
        #pragma unroll
        for (int cj = 0; cj < 4; ++cj) {
            const u16* kr = ksb + cj * 1024;
            bf16x8 k0 = *(const bf16x8*)(kr + koff0);
            bf16x8 k1 = *(const bf16x8*)(kr + koff1);
            f32x4 q4 = *(const f32x4*)(qsqg + s0 + cj*16 + quad*4);
            #pragma unroll
            for (int qi = 0; qi < 2; ++qi) {
                f32x4 acc = f32x4{0.f, 0.f, 0.f, 0.f};
                acc = __builtin_amdgcn_mfma_f32_16x16x32_bf16(k0, a0[qi], acc, 0, 0, 0);
                acc = __builtin_amdgcn_mfma_f32_16x16x32_bf16(k1, a1[qi], acc, 0, 0, 0);
                float p0 = __builtin_amdgcn_exp2f(fmaf(c2, acc[0], -fmaf(cf, q4[0], sqt[qi])));
                float p1 = __builtin_amdgcn_exp2f(fmaf(c2, acc[1], -fmaf(cf, q4[1], sqt[qi])));
                float p2 = __builtin_amdgcn_exp2f(fmaf(c2, acc[2], -fmaf(cf, q4[2], sqt[qi])));
                float p3 = __builtin_amdgcn_exp2f(fmaf(c2, acc[3], -fmaf(cf, q4[3], sqt[qi])));
                ssum[qi] += (p0 + p1) + (p2 + p3);
                uint2 pk;
                pk.x = cvtpk(p0, p1);
                pk.y = cvtpk(p2, p3);
                *(uint2*)&psw[(qi*16 + li)*LDP + cj*16 + quad*4] = pk;
            }
        }
        #pragma unroll
        for (int kj = 0; kj < 2; ++kj) {
            const int voff = (kj == 0) ? koff0 : koff1;   // same swizzle as K
            bf16x8 bv[4];
            #pragma unroll
            for (int dj = 0; dj < 4; ++dj)
                bv[dj] = *(const bf16x8*)(vtb + dj*1024 + voff);
            #pragma unroll
            for (int qi = 0; qi < 2; ++qi) {
                bf16x8 ap = *(const bf16x8*)&psw[(qi*16 + li)*LDP + kj*32 + quad*8];
                #pragma unroll
                for (int dj = 0; dj < 4; ++dj)
                    oacc[qi][dj] = __builtin_amdgcn_mfma_f32_16x16x32_bf16(
                        ap, bv[dj], oacc[qi][dj], 0, 0, 0);
            }
        }
    };

    // prologue: DMA tile 0 into buf0
    stage(ks0, vt0, 0);
    asm volatile("s_waitcnt vmcnt(0)" ::: "memory");
    __syncthreads();

    for (int t2 = 0; t2 < 16; ++t2) {
        const int t = 2 * t2;
        stage(ks1, vt1, t + 1);
        tile_compute(ks0, vt0, t * 64);
        asm volatile("s_waitcnt vmcnt(0)" ::: "memory");
        __syncthreads();
        if (t2 < 15) stage(ks0, vt0, t + 2);
        tile_compute(ks1, vt1, (t + 1) * 64);
        if (t2 < 15) {
            asm volatile("s_waitcnt vmcnt(0)" ::: "memory");
            __syncthreads();
        }
    }

    // denom: lane li holds t-col; reduce the 4 quad-partials, redistribute
    float inv[2][4];
    #pragma unroll
    for (int qi = 0; qi < 2; ++qi) {
        ssum[qi] += __shfl_xor(ssum[qi], 16, 64);
        ssum[qi] += __shfl_xor(ssum[qi], 32, 64);
        #pragma unroll
        for (int r = 0; r < 4; ++r)
            inv[qi][r] = 1.0f / __shfl(ssum[qi], quad*4 + r, 64);
    }

    // O lane layout: row t = quad*4+r, col d = li (+dj*16)
    #pragma unroll
    for (int qi = 0; qi < 2; ++qi)
        #pragma unroll
        for (int dj = 0; dj < 4; ++dj)
            #pragma unroll
            for (int r = 0; r < 4; ++r) {
                int t = qt0w + qi*16 + quad*4 + r;
                ao16[((size_t)(b*TT + t))*DIM + h*HD + dj*16 + li] =
                    f2bf(oacc[qi][dj][r] * inv[qi][r]);
            }
}

extern "C" void kernel_launch(void* const* d_in, const int* in_sizes, int n_in,
                              void* d_out, int out_size, void* d_ws, size_t ws_size,
                              hipStream_t stream)
{
    const float* x     = (const float*)d_in[0];   // [4,2048,512] f32
    const float* Wqkv  = (const float*)d_in[1];   // [512,1024]  f32
    const float* Wproj = (const float*)d_in[2];   // [512,512]   f32
    const float* bproj = (const float*)d_in[3];   // [512]       f32
    float* out = (float*)d_out;                   // [4,2048,512] f32

    char* ws = (char*)d_ws;
    const size_t MB = 1024*1024;
    u16*   q16  = (u16*)(ws);                          // 8 MB  [b,h,t,d] bf16
    u16*   vt16 = (u16*)(ws + 8*MB);                   // 8 MB  [b,h,d,t] bf16
    u16*   ao16 = (u16*)(ws + 16*MB);                  // 8 MB  [b,t,dim] bf16
    u16*   x16  = (u16*)(ws + 24*MB);                  // 8 MB  [b,t,dim] bf16
    u16*   Wtq  = (u16*)(ws + 32*MB);                  // 1 MB  [1024][512]
    u16*   Wtp  = (u16*)(ws + 33*MB);                  // 0.5MB [512][512]
    float* qsq  = (float*)(ws + 34*MB);                // 256 KB (16B aligned)
    float* asq  = (float*)(ws + 34*MB + 262144);       // 128 B
    u32* bmaxsq = (u32*)(ws + 34*MB + 262144 + 128);   // 16 B

    (void)in_sizes; (void)n_in; (void)out_size; (void)ws_size;

    hipMemsetAsync(ws + 34*MB + 262144, 0, 144, stream);

    prep_kernel<<<1024, 256, 0, stream>>>(x, x16, bmaxsq, Wqkv, Wtq, Wproj, Wtp);

    qkv_mfma<<<64*8, 256, 0, stream>>>(x16, Wtq, q16, vt16);

    qsq_kernel<<<BH*8, 256, 0, stream>>>(q16, qsq, asq);

    attn_kernel<<<BH*16, 256, 0, stream>>>(q16, vt16, qsq, asq, bmaxsq, ao16);

    proj_mfma<<<64*4, 256, 0, stream>>>(ao16, Wtp, bproj, out);
}

// Round 2
// 136.371 us; speedup vs baseline: 1.0838x; 1.0398x over previous
//
#include <hip/hip_runtime.h>
#include <hip/hip_bf16.h>

#define BB 4
#define TT 2048
#define DIM 512
#define NH 8
#define HD 64
#define NROW (BB*TT)   // 8192
#define BH (BB*NH)     // 32

typedef unsigned short u16;
typedef unsigned int u32;
typedef __attribute__((ext_vector_type(8))) short bf16x8;   // 8 bf16 = 4 VGPRs
typedef __attribute__((ext_vector_type(8))) unsigned short u16x8;
typedef __attribute__((ext_vector_type(4))) float f32x4;
typedef __attribute__((ext_vector_type(16))) float f32x16;
typedef __attribute__((ext_vector_type(4))) unsigned short u16x4;
typedef __attribute__((ext_vector_type(2))) unsigned int u32x2;

static __device__ __forceinline__ float bf2f(u16 u) {
    return __uint_as_float(((u32)u) << 16);
}
static __device__ __forceinline__ u16 f2bf(float f) {
    u32 u = __float_as_uint(f);
    u32 r = (u + 0x7FFFu + ((u >> 16) & 1u)) >> 16;
    return (u16)r;
}
// packed f32x2 -> bf16x2 (v_cvt_pk_bf16_f32 on gfx950)
static __device__ __forceinline__ u32 cvtpk(float a, float b) {
    union { __hip_bfloat162 h2; u32 u; } cv;
    cv.h2 = __float22bfloat162_rn(make_float2(a, b));
    return cv.u;
}
// async global -> LDS, 16B per lane. LDS dest = wave-uniform base + lane*16.
static __device__ __forceinline__ void gll16(const u16* g, u16* l) {
    __builtin_amdgcn_global_load_lds(
        (const __attribute__((address_space(1))) unsigned int*)g,
        (__attribute__((address_space(3))) unsigned int*)l,
        16, 0, 0);
}

// ---------------- prep: fused convert_x (blocks 0..255) + W transposes
__global__ __launch_bounds__(256) void prep_kernel(
    const float* __restrict__ x, u16* __restrict__ x16, u32* __restrict__ bmaxsq,
    const float* __restrict__ Wqkv, u16* __restrict__ Wtq,
    const float* __restrict__ Wproj, u16* __restrict__ Wtp)
{
    const int bid = blockIdx.x;
    const int tid = threadIdx.x;
    __shared__ u16 t[32][33];
    __shared__ float red[4];

    if (bid < 256) {
        const int row = bid * 32 + (tid >> 3);
        const int b = (bid * 32) >> 11;
        const float* xr = x   + (size_t)row * DIM + (tid & 7) * 64;
        u16*        xo  = x16 + (size_t)row * DIM + (tid & 7) * 64;
        float s = 0.0f;
        #pragma unroll
        for (int j = 0; j < 8; ++j) {
            float4 a = *(const float4*)(xr + j*8);
            float4 c = *(const float4*)(xr + j*8 + 4);
            s += a.x*a.x + a.y*a.y + a.z*a.z + a.w*a.w;
            s += c.x*c.x + c.y*c.y + c.z*c.z + c.w*c.w;
            u16x8 pk;
            pk[0]=f2bf(a.x); pk[1]=f2bf(a.y); pk[2]=f2bf(a.z); pk[3]=f2bf(a.w);
            pk[4]=f2bf(c.x); pk[5]=f2bf(c.y); pk[6]=f2bf(c.z); pk[7]=f2bf(c.w);
            *(u16x8*)(xo + j*8) = pk;
        }
        #pragma unroll
        for (int off = 1; off < 8; off <<= 1) s += __shfl_xor(s, off, 64);
        float m = s;
        #pragma unroll
        for (int off = 8; off < 64; off <<= 1) m = fmaxf(m, __shfl_xor(m, off, 64));
        if ((tid & 63) == 0) red[tid >> 6] = m;
        __syncthreads();
        if (tid == 0) {
            float mx = fmaxf(fmaxf(red[0], red[1]), fmaxf(red[2], red[3]));
            atomicMax(&bmaxsq[b], __float_as_uint(mx));
        }
    } else {
        const float* in; u16* outp; int K, N, tb;
        if (bid < 768) { in = Wqkv; outp = Wtq; K = 512; N = 1024; tb = bid - 256; }
        else           { in = Wproj; outp = Wtp; K = 512; N = 512;  tb = bid - 768; }
        const int ntiles = N >> 5;
        const int bx = tb % ntiles, by = tb / ntiles;
        const int n0 = bx * 32, k0 = by * 32;
        const int tx = tid & 31, ty = tid >> 5;
        #pragma unroll
        for (int i = 0; i < 32; i += 8)
            t[ty + i][tx] = f2bf(in[(size_t)(k0 + ty + i) * N + n0 + tx]);
        __syncthreads();
        #pragma unroll
        for (int i = 0; i < 32; i += 8)
            outp[(size_t)(n0 + ty + i) * K + k0 + tx] = t[tx][ty + i];
    }
}

// ---------------- MFMA GEMM: qkv = x16 @ Wqkv (via Wt [1024][512] bf16)
#define LDG 72
__global__ __launch_bounds__(256) void qkv_mfma(
    const u16* __restrict__ x16, const u16* __restrict__ Wt,
    u16* __restrict__ q16, u16* __restrict__ vt16)
{
    const int tid = threadIdx.x, lane = tid & 63, w = tid >> 6;
    const int li = lane & 15, quad = lane >> 4;
    const int mb = blockIdx.x >> 3, nb = blockIdx.x & 7;   // 64 x 8
    const int row0 = mb * 128, n0 = nb * 128;
    const int b = row0 >> 11;
    const int wm = w >> 1, wn = w & 1;

    __shared__ __align__(16) u16 as[128 * LDG];
    __shared__ __align__(16) u16 bs[128 * LDG];

    f32x4 acc[4][4];
    #pragma unroll
    for (int mi = 0; mi < 4; ++mi)
        #pragma unroll
        for (int ni = 0; ni < 4; ++ni) acc[mi][ni] = f32x4{0.f,0.f,0.f,0.f};

    for (int k0 = 0; k0 < DIM; k0 += 64) {
        __syncthreads();
        #pragma unroll
        for (int it = 0; it < 4; ++it) {
            int id = it * 256 + tid;
            int r = id >> 3, c = id & 7;
            *(bf16x8*)&as[r*LDG + c*8] =
                *(const bf16x8*)(x16 + (size_t)(row0 + r)*DIM + k0 + c*8);
            *(bf16x8*)&bs[r*LDG + c*8] =
                *(const bf16x8*)(Wt  + (size_t)(n0  + r)*DIM + k0 + c*8);
        }
        __syncthreads();

        bf16x8 af[4][2], bfr[4][2];
        #pragma unroll
        for (int mi = 0; mi < 4; ++mi) {
            const u16* p = &as[(wm*64 + mi*16 + li)*LDG + quad*8];
            af[mi][0] = *(const bf16x8*)p;
            af[mi][1] = *(const bf16x8*)(p + 32);
        }
        #pragma unroll
        for (int ni = 0; ni < 4; ++ni) {
            const u16* p = &bs[(wn*64 + ni*16 + li)*LDG + quad*8];
            bfr[ni][0] = *(const bf16x8*)p;
            bfr[ni][1] = *(const bf16x8*)(p + 32);
        }
        #pragma unroll
        for (int mi = 0; mi < 4; ++mi)
            #pragma unroll
            for (int ni = 0; ni < 4; ++ni) {
                acc[mi][ni] = __builtin_amdgcn_mfma_f32_16x16x32_bf16(
                    af[mi][0], bfr[ni][0], acc[mi][ni], 0, 0, 0);
                acc[mi][ni] = __builtin_amdgcn_mfma_f32_16x16x32_bf16(
                    af[mi][1], bfr[ni][1], acc[mi][ni], 0, 0, 0);
            }
    }

    const int h = li & 7;
    const bool isv = ((li >> 3) & 1) != 0;
    #pragma unroll
    for (int ni = 0; ni < 4; ++ni) {
        int col0 = n0 + wn*64 + ni*16;
        int d = col0 >> 4;
        #pragma unroll
        for (int mi = 0; mi < 4; ++mi) {
            int t0 = (row0 & (TT-1)) + wm*64 + mi*16 + quad*4;
            if (!isv) {
                u16* dst = q16 + ((size_t)(b*NH + h)*TT + t0)*HD + d;
                #pragma unroll
                for (int r = 0; r < 4; ++r)
                    dst[(size_t)r * HD] = f2bf(acc[mi][ni][r]);
            } else {
                u16x4 pk;
                pk.x = f2bf(acc[mi][ni][0]); pk.y = f2bf(acc[mi][ni][1]);
                pk.z = f2bf(acc[mi][ni][2]); pk.w = f2bf(acc[mi][ni][3]);
                *(u16x4*)(vt16 + ((size_t)(b*NH + h)*HD + d)*TT + t0) = pk;
            }
        }
    }
}

// ---------------- MFMA GEMM: out(f32) = ao16 @ Wproj + bias(f32)
__global__ __launch_bounds__(256) void proj_mfma(
    const u16* __restrict__ ao16, const u16* __restrict__ Wt,
    const float* __restrict__ bp, float* __restrict__ out)
{
    const int tid = threadIdx.x, lane = tid & 63, w = tid >> 6;
    const int li = lane & 15, quad = lane >> 4;
    const int mb = blockIdx.x >> 2, nb = blockIdx.x & 3;   // 64 x 4
    const int row0 = mb * 128, n0 = nb * 128;
    const int wm = w >> 1, wn = w & 1;

    __shared__ __align__(16) u16 as[128 * LDG];
    __shared__ __align__(16) u16 bs[128 * LDG];

    f32x4 acc[4][4];
    #pragma unroll
    for (int mi = 0; mi < 4; ++mi)
        #pragma unroll
        for (int ni = 0; ni < 4; ++ni) acc[mi][ni] = f32x4{0.f,0.f,0.f,0.f};

    for (int k0 = 0; k0 < DIM; k0 += 64) {
        __syncthreads();
        #pragma unroll
        for (int it = 0; it < 4; ++it) {
            int id = it * 256 + tid;
            int r = id >> 3, c = id & 7;
            *(bf16x8*)&as[r*LDG + c*8] =
                *(const bf16x8*)(ao16 + (size_t)(row0 + r)*DIM + k0 + c*8);
            *(bf16x8*)&bs[r*LDG + c*8] =
                *(const bf16x8*)(Wt   + (size_t)(n0  + r)*DIM + k0 + c*8);
        }
        __syncthreads();

        bf16x8 af[4][2], bfr[4][2];
        #pragma unroll
        for (int mi = 0; mi < 4; ++mi) {
            const u16* p = &as[(wm*64 + mi*16 + li)*LDG + quad*8];
            af[mi][0] = *(const bf16x8*)p;
            af[mi][1] = *(const bf16x8*)(p + 32);
        }
        #pragma unroll
        for (int ni = 0; ni < 4; ++ni) {
            const u16* p = &bs[(wn*64 + ni*16 + li)*LDG + quad*8];
            bfr[ni][0] = *(const bf16x8*)p;
            bfr[ni][1] = *(const bf16x8*)(p + 32);
        }
        #pragma unroll
        for (int mi = 0; mi < 4; ++mi)
            #pragma unroll
            for (int ni = 0; ni < 4; ++ni) {
                acc[mi][ni] = __builtin_amdgcn_mfma_f32_16x16x32_bf16(
                    af[mi][0], bfr[ni][0], acc[mi][ni], 0, 0, 0);
                acc[mi][ni] = __builtin_amdgcn_mfma_f32_16x16x32_bf16(
                    af[mi][1], bfr[ni][1], acc[mi][ni], 0, 0, 0);
            }
    }

    #pragma unroll
    for (int ni = 0; ni < 4; ++ni) {
        int col = n0 + wn*64 + ni*16 + li;
        float bias = bp[col];
        #pragma unroll
        for (int mi = 0; mi < 4; ++mi) {
            int r0 = row0 + wm*64 + mi*16 + quad*4;
            #pragma unroll
            for (int r = 0; r < 4; ++r)
                out[(size_t)(r0 + r)*DIM + col] = acc[mi][ni][r] + bias;
        }
    }
}

// ---------------- qsq: qsq[b,h,t] = sum_d q^2 ; asq[b,h] via 1 atomic/block
__global__ __launch_bounds__(256) void qsq_kernel(
    const u16* __restrict__ q16, float* __restrict__ qsq, float* __restrict__ asq)
{
    const int tid = threadIdx.x;
    const int bh = blockIdx.x >> 3;
    const int r0 = (blockIdx.x & 7) * 256;
    const u16* qb = q16 + ((size_t)bh * TT + r0) * HD;

    float tot = 0.0f;
    #pragma unroll
    for (int i = 0; i < 8; ++i) {
        int row = i * 32 + (tid >> 3);
        u16x8 v = *(const u16x8*)(qb + (size_t)row * HD + (tid & 7) * 8);
        float s = 0.0f;
        #pragma unroll
        for (int j = 0; j < 8; ++j) { float f = bf2f(v[j]); s += f * f; }
        tot += s;
        #pragma unroll
        for (int off = 1; off < 8; off <<= 1) s += __shfl_xor(s, off, 64);
        if ((tid & 7) == 0) qsq[(size_t)bh * TT + r0 + row] = s;
    }
    __shared__ float red[4];
    #pragma unroll
    for (int off = 32; off > 0; off >>= 1) tot += __shfl_down(tot, off, 64);
    if ((tid & 63) == 0) red[tid >> 6] = tot;
    __syncthreads();
    if (tid == 0) atomicAdd(&asq[bh], red[0] + red[1] + red[2] + red[3]);
}

// ---------------- attention v8:
// 32x32x16 MFMA, 4 waves x 32 q-rows. P built in-register via
// cvt_pk_bf16 + permlane32_swap (no P LDS round-trip). Per-row qsq_t
// term dropped (softmax-invariant). cf*qsq staged once into LDS.
// 4-buffer, 3-deep global_load_lds pipeline with counted vmcnt(8),
// one raw s_barrier per 64-s tile (no vmcnt(0) drain in loop).
__global__ __launch_bounds__(256) void attn_kernel(
    const u16* __restrict__ q16, const u16* __restrict__ vt16,
    const float* __restrict__ qsq, const float* __restrict__ asq,
    const u32* __restrict__ bmaxsq, u16* __restrict__ ao16)
{
    const int tid = threadIdx.x;
    const int lane = tid & 63, w = tid >> 6;          // 4 waves
    const int l31 = lane & 31, hf = lane >> 5;        // 32-col, half
    const int l7 = lane & 7;
    const int bh = blockIdx.x >> 4;                   // 32
    const int qtile = blockIdx.x & 15;                // 16 tiles x 128 q-rows
    const int b = bh >> 3, head = bh & 7;

    __shared__ __align__(16) u16 ksA[4][64 * 64];     // K bufs [s][d] swizzled
    __shared__ __align__(16) u16 vtA[4][64 * 64];     // V^T bufs [d][s] swizzled
    __shared__ __align__(16) float cq[TT];            // cf * qsq[s]
    __shared__ __align__(16) float invb[4 * 32];      // per-wave 1/ssum

    const u16* qg = q16  + (size_t)bh * TT * HD;      // [t][d]
    const u16* vg = vt16 + (size_t)bh * HD * TT;      // [d][t]
    const float* qsqg = qsq + (size_t)bh * TT;

    float cf;   // 100 * log2(e) / (a * bmax + eps)
    {
        float a  = sqrtf(asq[bh]);
        float bm = sqrtf(__uint_as_float(bmaxsq[b]));
        cf = (100.0f * 1.44269504089f) / (a * bm + 1e-10f);
    }
    const float c2 = 2.0f * cf;

    // Q B-frags: lane holds Q[t=l31][d = kc*16 + hf*8 + i]
    const int qt0w = qtile * 128 + w * 32;
    bf16x8 qf[4];
    {
        const u16* qrow = qg + (size_t)(qt0w + l31) * HD + hf * 8;
        #pragma unroll
        for (int kc = 0; kc < 4; ++kc)
            qf[kc] = *(const bf16x8*)(qrow + kc * 16);
    }

    // cq staging regs (8 floats per thread)
    const int ci = tid * 8;
    f32x4 cqa = *(const f32x4*)(qsqg + ci);
    f32x4 cqb = *(const f32x4*)(qsqg + ci + 4);

    // swizzled slot byte-offsets (elements): slot kc = ((2*kc + hf) ^ l7)*8
    int slot[4];
    #pragma unroll
    for (int kc = 0; kc < 4; ++kc) slot[kc] = (((2*kc + hf) ^ l7) << 3);

    // staging addresses (same inverse-swizzle as v7)
    const int rk = tid >> 3;
    const int ck = (tid & 7) ^ (rk & 7);
    const u16* kstg = qg + (size_t)rk * HD + ck * 8;  // + t*64*HD per tile
    const u16* vstg = vg + (size_t)rk * TT + ck * 8;  // + t*64 per tile
    const int lb0 = w * 512;                          // wave-uniform LDS base
    const int lb1 = 2048 + w * 512;

    auto stage = [&](int bi, int t) {
        const u16* kp = kstg + (size_t)t * 64 * HD;
        const u16* vp = vstg + t * 64;
        gll16(kp,                 &ksA[bi][0] + lb0);
        gll16(kp + 32 * HD,       &ksA[bi][0] + lb1);
        gll16(vp,                 &vtA[bi][0] + lb0);
        gll16(vp + (size_t)32*TT, &vtA[bi][0] + lb1);
    };

    float ssum = 0.0f;
    f32x16 oacc[2];
    #pragma unroll
    for (int dh = 0; dh < 2; ++dh)
        #pragma unroll
        for (int r = 0; r < 16; ++r) oacc[dh][r] = 0.0f;

    auto tile_compute = [&](const u16* __restrict__ ksb,
                            const u16* __restrict__ vtb, int s0) {
        bf16x8 pa[4];
        #pragma unroll
        for (int sc = 0; sc < 2; ++sc) {
            const u16* kbase = ksb + sc * 2048 + l31 * 64;
            bf16x8 kf0 = *(const bf16x8*)(kbase + slot[0]);
            bf16x8 kf1 = *(const bf16x8*)(kbase + slot[1]);
            bf16x8 kf2 = *(const bf16x8*)(kbase + slot[2]);
            bf16x8 kf3 = *(const bf16x8*)(kbase + slot[3]);
            f32x16 acc;
            #pragma unroll
            for (int r = 0; r < 16; ++r) acc[r] = 0.0f;
            acc = __builtin_amdgcn_mfma_f32_32x32x16_bf16(kf0, qf[0], acc, 0, 0, 0);
            acc = __builtin_amdgcn_mfma_f32_32x32x16_bf16(kf1, qf[1], acc, 0, 0, 0);
            acc = __builtin_amdgcn_mfma_f32_32x32x16_bf16(kf2, qf[2], acc, 0, 0, 0);
            acc = __builtin_amdgcn_mfma_f32_32x32x16_bf16(kf3, qf[3], acc, 0, 0, 0);
            // softmax (qsq_t dropped: cancels in P*V / sum(P))
            float p[16];
            #pragma unroll
            for (int g = 0; g < 4; ++g) {
                f32x4 cq4 = *(const f32x4*)&cq[s0 + sc*32 + g*8 + hf*4];
                p[4*g+0] = __builtin_amdgcn_exp2f(fmaf(c2, acc[4*g+0], -cq4[0]));
                p[4*g+1] = __builtin_amdgcn_exp2f(fmaf(c2, acc[4*g+1], -cq4[1]));
                p[4*g+2] = __builtin_amdgcn_exp2f(fmaf(c2, acc[4*g+2], -cq4[2]));
                p[4*g+3] = __builtin_amdgcn_exp2f(fmaf(c2, acc[4*g+3], -cq4[3]));
            }
            ssum += (((p[0]+p[1])+(p[2]+p[3])) + ((p[4]+p[5])+(p[6]+p[7])))
                  + (((p[8]+p[9])+(p[10]+p[11])) + ((p[12]+p[13])+(p[14]+p[15])));
            // build PV A-frags: words {0,2} = swap(pk(p[8k],p[8k+1]), pk(p[8k+4],p[8k+5]))
            #pragma unroll
            for (int kh = 0; kh < 2; ++kh) {
                u32 A0 = cvtpk(p[8*kh+0], p[8*kh+1]);
                u32 B0 = cvtpk(p[8*kh+4], p[8*kh+5]);
                u32 A1 = cvtpk(p[8*kh+2], p[8*kh+3]);
                u32 B1 = cvtpk(p[8*kh+6], p[8*kh+7]);
                u32x2 r0 = __builtin_amdgcn_permlane32_swap(A0, B0, false, false);
                u32x2 r1 = __builtin_amdgcn_permlane32_swap(A1, B1, false, false);
                union { u32 u[4]; bf16x8 v; } pw;
                pw.u[0] = r0.x; pw.u[1] = r1.x; pw.u[2] = r0.y; pw.u[3] = r1.y;
                pa[sc*2 + kh] = pw.v;
            }
        }
        // PV: O[t][d] += P[t][s] * V[s][d]
        #pragma unroll
        for (int kc2 = 0; kc2 < 4; ++kc2) {
            #pragma unroll
            for (int dh = 0; dh < 2; ++dh) {
                const u16* vr = vtb + (dh*32 + l31) * 64 + slot[kc2];
                bf16x8 vf = *(const bf16x8*)vr;
                oacc[dh] = __builtin_amdgcn_mfma_f32_32x32x16_bf16(
                    pa[kc2], vf, oacc[dh], 0, 0, 0);
            }
        }
    };

    // prologue: 3-deep prefetch + cq table
    stage(0, 0); stage(1, 1); stage(2, 2);
    *(f32x4*)&cq[ci]     = cqa * cf;
    *(f32x4*)&cq[ci + 4] = cqb * cf;
    asm volatile("s_waitcnt lgkmcnt(0)" ::: "memory");
    __builtin_amdgcn_s_barrier();

    #pragma unroll 1
    for (int m = 0; m < 7; ++m) {
        const int i0 = m * 4;
        #pragma unroll
        for (int j = 0; j < 4; ++j) {
            asm volatile("s_waitcnt vmcnt(8)" ::: "memory");
            __builtin_amdgcn_s_barrier();
            stage((j + 3) & 3, i0 + j + 3);
            tile_compute(&ksA[j][0], &vtA[j][0], (i0 + j) * 64);
        }
    }
    // epilogue tiles 28..31
    asm volatile("s_waitcnt vmcnt(8)" ::: "memory");
    __builtin_amdgcn_s_barrier();
    stage(3, 31);
    tile_compute(&ksA[0][0], &vtA[0][0], 28 * 64);
    asm volatile("s_waitcnt vmcnt(8)" ::: "memory");
    __builtin_amdgcn_s_barrier();
    tile_compute(&ksA[1][0], &vtA[1][0], 29 * 64);
    asm volatile("s_waitcnt vmcnt(4)" ::: "memory");
    __builtin_amdgcn_s_barrier();
    tile_compute(&ksA[2][0], &vtA[2][0], 30 * 64);
    asm volatile("s_waitcnt vmcnt(0)" ::: "memory");
    __builtin_amdgcn_s_barrier();
    tile_compute(&ksA[3][0], &vtA[3][0], 31 * 64);

    // denom: lane l31 holds t-col; halves hold disjoint s-subsets
    ssum += __shfl_xor(ssum, 32, 64);
    if (hf == 0) invb[w*32 + l31] = 1.0f / ssum;
    // per-wave private region; same-wave RAW handled by lgkm waits

    // O layout: col d = l31 (+dh*32), row t = (reg&3) + 8*(reg>>2) + 4*hf
    #pragma unroll
    for (int g = 0; g < 4; ++g) {
        f32x4 iv4 = *(const f32x4*)&invb[w*32 + g*8 + hf*4];
        #pragma unroll
        for (int dh = 0; dh < 2; ++dh) {
            #pragma unroll
            for (int r0 = 0; r0 < 4; ++r0) {
                int t = qt0w + g*8 + hf*4 + r0;
                ao16[((size_t)(b*TT + t))*DIM + head*HD + dh*32 + l31] =
                    f2bf(oacc[dh][g*4 + r0] * iv4[r0]);
            }
        }
    }
}

extern "C" void kernel_launch(void* const* d_in, const int* in_sizes, int n_in,
                              void* d_out, int out_size, void* d_ws, size_t ws_size,
                              hipStream_t stream)
{
    const float* x     = (const float*)d_in[0];   // [4,2048,512] f32
    const float* Wqkv  = (const float*)d_in[1];   // [512,1024]  f32
    const float* Wproj = (const float*)d_in[2];   // [512,512]   f32
    const float* bproj = (const float*)d_in[3];   // [512]       f32
    float* out = (float*)d_out;                   // [4,2048,512] f32

    char* ws = (char*)d_ws;
    const size_t MB = 1024*1024;
    u16*   q16  = (u16*)(ws);                          // 8 MB  [b,h,t,d] bf16
    u16*   vt16 = (u16*)(ws + 8*MB);                   // 8 MB  [b,h,d,t] bf16
    u16*   ao16 = (u16*)(ws + 16*MB);                  // 8 MB  [b,t,dim] bf16
    u16*   x16  = (u16*)(ws + 24*MB);                  // 8 MB  [b,t,dim] bf16
    u16*   Wtq  = (u16*)(ws + 32*MB);                  // 1 MB  [1024][512]
    u16*   Wtp  = (u16*)(ws + 33*MB);                  // 0.5MB [512][512]
    float* qsq  = (float*)(ws + 34*MB);                // 256 KB (16B aligned)
    float* asq  = (float*)(ws + 34*MB + 262144);       // 128 B
    u32* bmaxsq = (u32*)(ws + 34*MB + 262144 + 128);   // 16 B

    (void)in_sizes; (void)n_in; (void)out_size; (void)ws_size;

    hipMemsetAsync(ws + 34*MB + 262144, 0, 144, stream);

    prep_kernel<<<1024, 256, 0, stream>>>(x, x16, bmaxsq, Wqkv, Wtq, Wproj, Wtp);

    qkv_mfma<<<64*8, 256, 0, stream>>>(x16, Wtq, q16, vt16);

    qsq_kernel<<<BH*8, 256, 0, stream>>>(q16, qsq, asq);

    attn_kernel<<<BH*16, 256, 0, stream>>>(q16, vt16, qsq, asq, bmaxsq, ao16);

    proj_mfma<<<64*4, 256, 0, stream>>>(ao16, Wtp, bproj, out);
}

// Round 3
// 132.759 us; speedup vs baseline: 1.1133x; 1.0272x over previous
//
#include <hip/hip_runtime.h>
#include <hip/hip_bf16.h>

#define BB 4
#define TT 2048
#define DIM 512
#define NH 8
#define HD 64
#define NROW (BB*TT)   // 8192
#define BH (BB*NH)     // 32

typedef unsigned short u16;
typedef unsigned int u32;
typedef __attribute__((ext_vector_type(8))) short bf16x8;   // 8 bf16 = 4 VGPRs
typedef __attribute__((ext_vector_type(8))) unsigned short u16x8;
typedef __attribute__((ext_vector_type(4))) float f32x4;
typedef __attribute__((ext_vector_type(16))) float f32x16;
typedef __attribute__((ext_vector_type(4))) unsigned short u16x4;
typedef __attribute__((ext_vector_type(2))) unsigned int u32x2;

static __device__ __forceinline__ float bf2f(u16 u) {
    return __uint_as_float(((u32)u) << 16);
}
static __device__ __forceinline__ u16 f2bf(float f) {
    u32 u = __float_as_uint(f);
    u32 r = (u + 0x7FFFu + ((u >> 16) & 1u)) >> 16;
    return (u16)r;
}
// packed f32x2 -> bf16x2 (v_cvt_pk_bf16_f32 on gfx950)
static __device__ __forceinline__ u32 cvtpk(float a, float b) {
    union { __hip_bfloat162 h2; u32 u; } cv;
    cv.h2 = __float22bfloat162_rn(make_float2(a, b));
    return cv.u;
}
// async global -> LDS, 16B per lane. LDS dest = wave-uniform base + lane*16.
static __device__ __forceinline__ void gll16(const u16* g, u16* l) {
    __builtin_amdgcn_global_load_lds(
        (const __attribute__((address_space(1))) unsigned int*)g,
        (__attribute__((address_space(3))) unsigned int*)l,
        16, 0, 0);
}

// ---------------- prep: fused convert_x (blocks 0..255) + W transposes
__global__ __launch_bounds__(256) void prep_kernel(
    const float* __restrict__ x, u16* __restrict__ x16, u32* __restrict__ bmaxsq,
    const float* __restrict__ Wqkv, u16* __restrict__ Wtq,
    const float* __restrict__ Wproj, u16* __restrict__ Wtp)
{
    const int bid = blockIdx.x;
    const int tid = threadIdx.x;
    __shared__ u16 t[32][33];
    __shared__ float red[4];

    if (bid < 256) {
        const int row = bid * 32 + (tid >> 3);
        const int b = (bid * 32) >> 11;
        const float* xr = x   + (size_t)row * DIM + (tid & 7) * 64;
        u16*        xo  = x16 + (size_t)row * DIM + (tid & 7) * 64;
        float s = 0.0f;
        #pragma unroll
        for (int j = 0; j < 8; ++j) {
            float4 a = *(const float4*)(xr + j*8);
            float4 c = *(const float4*)(xr + j*8 + 4);
            s += a.x*a.x + a.y*a.y + a.z*a.z + a.w*a.w;
            s += c.x*c.x + c.y*c.y + c.z*c.z + c.w*c.w;
            u16x8 pk;
            pk[0]=f2bf(a.x); pk[1]=f2bf(a.y); pk[2]=f2bf(a.z); pk[3]=f2bf(a.w);
            pk[4]=f2bf(c.x); pk[5]=f2bf(c.y); pk[6]=f2bf(c.z); pk[7]=f2bf(c.w);
            *(u16x8*)(xo + j*8) = pk;
        }
        #pragma unroll
        for (int off = 1; off < 8; off <<= 1) s += __shfl_xor(s, off, 64);
        float m = s;
        #pragma unroll
        for (int off = 8; off < 64; off <<= 1) m = fmaxf(m, __shfl_xor(m, off, 64));
        if ((tid & 63) == 0) red[tid >> 6] = m;
        __syncthreads();
        if (tid == 0) {
            float mx = fmaxf(fmaxf(red[0], red[1]), fmaxf(red[2], red[3]));
            atomicMax(&bmaxsq[b], __float_as_uint(mx));
        }
    } else {
        const float* in; u16* outp; int K, N, tb;
        if (bid < 768) { in = Wqkv; outp = Wtq; K = 512; N = 1024; tb = bid - 256; }
        else           { in = Wproj; outp = Wtp; K = 512; N = 512;  tb = bid - 768; }
        const int ntiles = N >> 5;
        const int bx = tb % ntiles, by = tb / ntiles;
        const int n0 = bx * 32, k0 = by * 32;
        const int tx = tid & 31, ty = tid >> 5;
        #pragma unroll
        for (int i = 0; i < 32; i += 8)
            t[ty + i][tx] = f2bf(in[(size_t)(k0 + ty + i) * N + n0 + tx]);
        __syncthreads();
        #pragma unroll
        for (int i = 0; i < 32; i += 8)
            outp[(size_t)(n0 + ty + i) * K + k0 + tx] = t[tx][ty + i];
    }
}

// ---------------- MFMA GEMM: qkv = x16 @ Wqkv (via Wt [1024][512] bf16)
#define LDG 72
__global__ __launch_bounds__(256) void qkv_mfma(
    const u16* __restrict__ x16, const u16* __restrict__ Wt,
    u16* __restrict__ q16, u16* __restrict__ vt16)
{
    const int tid = threadIdx.x, lane = tid & 63, w = tid >> 6;
    const int li = lane & 15, quad = lane >> 4;
    const int mb = blockIdx.x >> 3, nb = blockIdx.x & 7;   // 64 x 8
    const int row0 = mb * 128, n0 = nb * 128;
    const int b = row0 >> 11;
    const int wm = w >> 1, wn = w & 1;

    __shared__ __align__(16) u16 as[128 * LDG];
    __shared__ __align__(16) u16 bs[128 * LDG];

    f32x4 acc[4][4];
    #pragma unroll
    for (int mi = 0; mi < 4; ++mi)
        #pragma unroll
        for (int ni = 0; ni < 4; ++ni) acc[mi][ni] = f32x4{0.f,0.f,0.f,0.f};

    for (int k0 = 0; k0 < DIM; k0 += 64) {
        __syncthreads();
        #pragma unroll
        for (int it = 0; it < 4; ++it) {
            int id = it * 256 + tid;
            int r = id >> 3, c = id & 7;
            *(bf16x8*)&as[r*LDG + c*8] =
                *(const bf16x8*)(x16 + (size_t)(row0 + r)*DIM + k0 + c*8);
            *(bf16x8*)&bs[r*LDG + c*8] =
                *(const bf16x8*)(Wt  + (size_t)(n0  + r)*DIM + k0 + c*8);
        }
        __syncthreads();

        bf16x8 af[4][2], bfr[4][2];
        #pragma unroll
        for (int mi = 0; mi < 4; ++mi) {
            const u16* p = &as[(wm*64 + mi*16 + li)*LDG + quad*8];
            af[mi][0] = *(const bf16x8*)p;
            af[mi][1] = *(const bf16x8*)(p + 32);
        }
        #pragma unroll
        for (int ni = 0; ni < 4; ++ni) {
            const u16* p = &bs[(wn*64 + ni*16 + li)*LDG + quad*8];
            bfr[ni][0] = *(const bf16x8*)p;
            bfr[ni][1] = *(const bf16x8*)(p + 32);
        }
        #pragma unroll
        for (int mi = 0; mi < 4; ++mi)
            #pragma unroll
            for (int ni = 0; ni < 4; ++ni) {
                acc[mi][ni] = __builtin_amdgcn_mfma_f32_16x16x32_bf16(
                    af[mi][0], bfr[ni][0], acc[mi][ni], 0, 0, 0);
                acc[mi][ni] = __builtin_amdgcn_mfma_f32_16x16x32_bf16(
                    af[mi][1], bfr[ni][1], acc[mi][ni], 0, 0, 0);
            }
    }

    const int h = li & 7;
    const bool isv = ((li >> 3) & 1) != 0;
    #pragma unroll
    for (int ni = 0; ni < 4; ++ni) {
        int col0 = n0 + wn*64 + ni*16;
        int d = col0 >> 4;
        #pragma unroll
        for (int mi = 0; mi < 4; ++mi) {
            int t0 = (row0 & (TT-1)) + wm*64 + mi*16 + quad*4;
            if (!isv) {
                u16* dst = q16 + ((size_t)(b*NH + h)*TT + t0)*HD + d;
                #pragma unroll
                for (int r = 0; r < 4; ++r)
                    dst[(size_t)r * HD] = f2bf(acc[mi][ni][r]);
            } else {
                u16x4 pk;
                pk.x = f2bf(acc[mi][ni][0]); pk.y = f2bf(acc[mi][ni][1]);
                pk.z = f2bf(acc[mi][ni][2]); pk.w = f2bf(acc[mi][ni][3]);
                *(u16x4*)(vt16 + ((size_t)(b*NH + h)*HD + d)*TT + t0) = pk;
            }
        }
    }
}

// ---------------- MFMA GEMM: out(f32) = ao16 @ Wproj + bias(f32)
__global__ __launch_bounds__(256) void proj_mfma(
    const u16* __restrict__ ao16, const u16* __restrict__ Wt,
    const float* __restrict__ bp, float* __restrict__ out)
{
    const int tid = threadIdx.x, lane = tid & 63, w = tid >> 6;
    const int li = lane & 15, quad = lane >> 4;
    const int mb = blockIdx.x >> 2, nb = blockIdx.x & 3;   // 64 x 4
    const int row0 = mb * 128, n0 = nb * 128;
    const int wm = w >> 1, wn = w & 1;

    __shared__ __align__(16) u16 as[128 * LDG];
    __shared__ __align__(16) u16 bs[128 * LDG];

    f32x4 acc[4][4];
    #pragma unroll
    for (int mi = 0; mi < 4; ++mi)
        #pragma unroll
        for (int ni = 0; ni < 4; ++ni) acc[mi][ni] = f32x4{0.f,0.f,0.f,0.f};

    for (int k0 = 0; k0 < DIM; k0 += 64) {
        __syncthreads();
        #pragma unroll
        for (int it = 0; it < 4; ++it) {
            int id = it * 256 + tid;
            int r = id >> 3, c = id & 7;
            *(bf16x8*)&as[r*LDG + c*8] =
                *(const bf16x8*)(ao16 + (size_t)(row0 + r)*DIM + k0 + c*8);
            *(bf16x8*)&bs[r*LDG + c*8] =
                *(const bf16x8*)(Wt   + (size_t)(n0  + r)*DIM + k0 + c*8);
        }
        __syncthreads();

        bf16x8 af[4][2], bfr[4][2];
        #pragma unroll
        for (int mi = 0; mi < 4; ++mi) {
            const u16* p = &as[(wm*64 + mi*16 + li)*LDG + quad*8];
            af[mi][0] = *(const bf16x8*)p;
            af[mi][1] = *(const bf16x8*)(p + 32);
        }
        #pragma unroll
        for (int ni = 0; ni < 4; ++ni) {
            const u16* p = &bs[(wn*64 + ni*16 + li)*LDG + quad*8];
            bfr[ni][0] = *(const bf16x8*)p;
            bfr[ni][1] = *(const bf16x8*)(p + 32);
        }
        #pragma unroll
        for (int mi = 0; mi < 4; ++mi)
            #pragma unroll
            for (int ni = 0; ni < 4; ++ni) {
                acc[mi][ni] = __builtin_amdgcn_mfma_f32_16x16x32_bf16(
                    af[mi][0], bfr[ni][0], acc[mi][ni], 0, 0, 0);
                acc[mi][ni] = __builtin_amdgcn_mfma_f32_16x16x32_bf16(
                    af[mi][1], bfr[ni][1], acc[mi][ni], 0, 0, 0);
            }
    }

    #pragma unroll
    for (int ni = 0; ni < 4; ++ni) {
        int col = n0 + wn*64 + ni*16 + li;
        float bias = bp[col];
        #pragma unroll
        for (int mi = 0; mi < 4; ++mi) {
            int r0 = row0 + wm*64 + mi*16 + quad*4;
            #pragma unroll
            for (int r = 0; r < 4; ++r)
                out[(size_t)(r0 + r)*DIM + col] = acc[mi][ni][r] + bias;
        }
    }
}

// ---------------- qsq: qsq[b,h,t] = sum_d q^2 ; asq[b,h] via 1 atomic/block
__global__ __launch_bounds__(256) void qsq_kernel(
    const u16* __restrict__ q16, float* __restrict__ qsq, float* __restrict__ asq)
{
    const int tid = threadIdx.x;
    const int bh = blockIdx.x >> 3;
    const int r0 = (blockIdx.x & 7) * 256;
    const u16* qb = q16 + ((size_t)bh * TT + r0) * HD;

    float tot = 0.0f;
    #pragma unroll
    for (int i = 0; i < 8; ++i) {
        int row = i * 32 + (tid >> 3);
        u16x8 v = *(const u16x8*)(qb + (size_t)row * HD + (tid & 7) * 8);
        float s = 0.0f;
        #pragma unroll
        for (int j = 0; j < 8; ++j) { float f = bf2f(v[j]); s += f * f; }
        tot += s;
        #pragma unroll
        for (int off = 1; off < 8; off <<= 1) s += __shfl_xor(s, off, 64);
        if ((tid & 7) == 0) qsq[(size_t)bh * TT + r0 + row] = s;
    }
    __shared__ float red[4];
    #pragma unroll
    for (int off = 32; off > 0; off >>= 1) tot += __shfl_down(tot, off, 64);
    if ((tid & 63) == 0) red[tid >> 6] = tot;
    __syncthreads();
    if (tid == 0) atomicAdd(&asq[bh], red[0] + red[1] + red[2] + red[3]);
}

// ---------------- attention v9:
// 64 q-rows per wave (2x operand reuse: each K/V frag read feeds 2 MFMAs).
// Wave pairs split s: waves {0,1} own q-rows 0-63 (even/odd s-tiles),
// waves {2,3} own rows 64-127. Flash combine of s-partials once at end
// via LDS (overlaid on K/V ring). Denominator via ones-column MFMA
// (sum_s P = P*1) -- no VALU adds, no cross-lane reduce: ones-acc rows
// map 1:1 to O-acc rows. 4-buffer (2-pair) ring, counted vmcnt(8),
// 2 barriers per 2-tile pair.
__global__ __launch_bounds__(256, 2) void attn_kernel(
    const u16* __restrict__ q16, const u16* __restrict__ vt16,
    const float* __restrict__ qsq, const float* __restrict__ asq,
    const u32* __restrict__ bmaxsq, u16* __restrict__ ao16)
{
    const int tid = threadIdx.x;
    const int lane = tid & 63, w = tid >> 6;          // 4 waves
    const int l31 = lane & 31, hf = lane >> 5;
    const int l7 = lane & 7;
    const int ws = w & 1;                             // s-parity within pair
    const int p  = w >> 1;                            // q-pair (rows p*64..)
    const int bh = blockIdx.x >> 4;                   // 32
    const int qtile = blockIdx.x & 15;                // 16 tiles x 128 q-rows
    const int b = bh >> 3, head = bh & 7;

    // smem carve: 4 K bufs (32KB) | 4 V bufs (32KB) | cq (8KB)  = 72KB
    __shared__ __align__(16) u16 smem[36864];
    u16* ksA = smem;                 // [4][64*64] swizzled K [s][d]
    u16* vtA = smem + 16384;         // [4][64*64] swizzled V^T [d][s]
    float* cq = (float*)(smem + 32768);   // cf * qsq[s], s in [0,2048)

    const u16* qgp = q16  + (size_t)bh * TT * HD;     // [t][d]
    const u16* vgp = vt16 + (size_t)bh * HD * TT;     // [d][t]
    const float* qsqg = qsq + (size_t)bh * TT;

    float cf;   // 100 * log2(e) / (a * bmax + eps)
    {
        float a  = sqrtf(asq[bh]);
        float bm = sqrtf(__uint_as_float(bmaxsq[b]));
        cf = (100.0f * 1.44269504089f) / (a * bm + 1e-10f);
    }
    const float c2 = 2.0f * cf;

    // Q B-frags for 2 row-groups: lane holds Q[t=qt0+qg*32+l31][kc*16+hf*8+i]
    const int qt0 = qtile * 128 + p * 64;
    bf16x8 qf[2][4];
    #pragma unroll
    for (int qg = 0; qg < 2; ++qg) {
        const u16* qrow = qgp + (size_t)(qt0 + qg*32 + l31) * HD + hf * 8;
        #pragma unroll
        for (int kc = 0; kc < 4; ++kc)
            qf[qg][kc] = *(const bf16x8*)(qrow + kc * 16);
    }

    // cq staging regs (8 floats per thread)
    const int ci = tid * 8;
    f32x4 cqa = *(const f32x4*)(qsqg + ci);
    f32x4 cqb = *(const f32x4*)(qsqg + ci + 4);

    // swizzled slot offsets (elements): slot kc = ((2*kc + hf) ^ l7)*8
    int slot[4];
    #pragma unroll
    for (int kc = 0; kc < 4; ++kc) slot[kc] = (((2*kc + hf) ^ l7) << 3);

    // staging addresses (inverse-swizzled global source, linear LDS dest)
    const int rk = tid >> 3;
    const int ck = (tid & 7) ^ (rk & 7);
    const u16* kstg = qgp + (size_t)rk * HD + ck * 8;  // + t*64*HD per tile
    const u16* vstg = vgp + (size_t)rk * TT + ck * 8;  // + t*64 per tile
    const int lb0 = w * 512;                           // wave-uniform LDS base
    const int lb1 = 2048 + w * 512;

    // stage a PAIR of tiles {t0g, t0g+1} into ring slots {sb, sb+1}
    auto stagePair = [&](int sb, int t0g) {
        #pragma unroll
        for (int ts = 0; ts < 2; ++ts) {
            const u16* kp = kstg + (size_t)(t0g + ts) * 64 * HD;
            const u16* vp = vstg + (t0g + ts) * 64;
            u16* kb = ksA + (sb + ts) * 4096;
            u16* vb = vtA + (sb + ts) * 4096;
            gll16(kp,                 kb + lb0);
            gll16(kp + 32 * HD,       kb + lb1);
            gll16(vp,                 vb + lb0);
            gll16(vp + (size_t)32*TT, vb + lb1);
        }
    };

    // ones B-frag for denominator MFMA
    bf16x8 onesf;
    {
        union { u16 a[8]; bf16x8 v; } o;
        #pragma unroll
        for (int i = 0; i < 8; ++i) o.a[i] = 0x3F80;
        onesf = o.v;
    }

    f32x16 oacc[2][2], osum[2];
    #pragma unroll
    for (int qg = 0; qg < 2; ++qg) {
        #pragma unroll
        for (int r = 0; r < 16; ++r) { oacc[qg][0][r] = 0.f; oacc[qg][1][r] = 0.f; osum[qg][r] = 0.f; }
    }

    auto tile_compute = [&](const u16* __restrict__ ksb,
                            const u16* __restrict__ vtb, int s0) {
        bf16x8 pa[2][4];
        #pragma unroll
        for (int sc = 0; sc < 2; ++sc) {
            const u16* kbase = ksb + sc * 2048 + l31 * 64;
            bf16x8 kf0 = *(const bf16x8*)(kbase + slot[0]);
            bf16x8 kf1 = *(const bf16x8*)(kbase + slot[1]);
            bf16x8 kf2 = *(const bf16x8*)(kbase + slot[2]);
            bf16x8 kf3 = *(const bf16x8*)(kbase + slot[3]);
            f32x4 cq4[4];
            #pragma unroll
            for (int g = 0; g < 4; ++g)
                cq4[g] = *(const f32x4*)&cq[s0 + sc*32 + g*8 + hf*4];
            #pragma unroll
            for (int qg = 0; qg < 2; ++qg) {
                f32x16 acc;
                #pragma unroll
                for (int r = 0; r < 16; ++r) acc[r] = 0.0f;
                __builtin_amdgcn_s_setprio(1);
                acc = __builtin_amdgcn_mfma_f32_32x32x16_bf16(kf0, qf[qg][0], acc, 0, 0, 0);
                acc = __builtin_amdgcn_mfma_f32_32x32x16_bf16(kf1, qf[qg][1], acc, 0, 0, 0);
                acc = __builtin_amdgcn_mfma_f32_32x32x16_bf16(kf2, qf[qg][2], acc, 0, 0, 0);
                acc = __builtin_amdgcn_mfma_f32_32x32x16_bf16(kf3, qf[qg][3], acc, 0, 0, 0);
                __builtin_amdgcn_s_setprio(0);
                float pv[16];
                #pragma unroll
                for (int g = 0; g < 4; ++g) {
                    pv[4*g+0] = __builtin_amdgcn_exp2f(fmaf(c2, acc[4*g+0], -cq4[g][0]));
                    pv[4*g+1] = __builtin_amdgcn_exp2f(fmaf(c2, acc[4*g+1], -cq4[g][1]));
                    pv[4*g+2] = __builtin_amdgcn_exp2f(fmaf(c2, acc[4*g+2], -cq4[g][2]));
                    pv[4*g+3] = __builtin_amdgcn_exp2f(fmaf(c2, acc[4*g+3], -cq4[g][3]));
                }
                #pragma unroll
                for (int kh = 0; kh < 2; ++kh) {
                    u32 A0 = cvtpk(pv[8*kh+0], pv[8*kh+1]);
                    u32 B0 = cvtpk(pv[8*kh+4], pv[8*kh+5]);
                    u32 A1 = cvtpk(pv[8*kh+2], pv[8*kh+3]);
                    u32 B1 = cvtpk(pv[8*kh+6], pv[8*kh+7]);
                    u32x2 r0 = __builtin_amdgcn_permlane32_swap(A0, B0, false, false);
                    u32x2 r1 = __builtin_amdgcn_permlane32_swap(A1, B1, false, false);
                    union { u32 u[4]; bf16x8 v; } pw;
                    pw.u[0] = r0.x; pw.u[1] = r1.x; pw.u[2] = r0.y; pw.u[3] = r1.y;
                    pa[qg][sc*2 + kh] = pw.v;
                }
            }
        }
        // PV + denominator: each V frag feeds 2 qg; ones-MFMA row-sums P
        #pragma unroll
        for (int kc = 0; kc < 4; ++kc) {
            bf16x8 vf0 = *(const bf16x8*)(vtb + (0*32 + l31) * 64 + slot[kc]);
            bf16x8 vf1 = *(const bf16x8*)(vtb + (1*32 + l31) * 64 + slot[kc]);
            __builtin_amdgcn_s_setprio(1);
            #pragma unroll
            for (int qg = 0; qg < 2; ++qg) {
                oacc[qg][0] = __builtin_amdgcn_mfma_f32_32x32x16_bf16(
                    pa[qg][kc], vf0, oacc[qg][0], 0, 0, 0);
                oacc[qg][1] = __builtin_amdgcn_mfma_f32_32x32x16_bf16(
                    pa[qg][kc], vf1, oacc[qg][1], 0, 0, 0);
                osum[qg] = __builtin_amdgcn_mfma_f32_32x32x16_bf16(
                    pa[qg][kc], onesf, osum[qg], 0, 0, 0);
            }
            __builtin_amdgcn_s_setprio(0);
        }
    };

    // prologue: stage pairs 0,1 (tiles 0..3); cq table
    stagePair(0, 0);
    stagePair(2, 2);
    *(f32x4*)&cq[ci]     = cqa * cf;
    *(f32x4*)&cq[ci + 4] = cqb * cf;
    asm volatile("s_waitcnt lgkmcnt(0)" ::: "memory");
    __builtin_amdgcn_s_barrier();

    // 16 pairs of tiles; wave computes tile 2m+ws of pair m
    #pragma unroll 2
    for (int m = 0; m < 15; ++m) {
        asm volatile("s_waitcnt vmcnt(8)" ::: "memory");
        __builtin_amdgcn_s_barrier();
        const int sb = (m & 1) * 2;
        tile_compute(ksA + (sb + ws) * 4096, vtA + (sb + ws) * 4096,
                     (2*m + ws) * 64);
        __builtin_amdgcn_s_barrier();
        if (m <= 13) stagePair(sb, 2*(m + 2));
    }
    asm volatile("s_waitcnt vmcnt(0)" ::: "memory");
    __builtin_amdgcn_s_barrier();
    tile_compute(ksA + (2 + ws) * 4096, vtA + (2 + ws) * 4096,
                 (30 + ws) * 64);
    __builtin_amdgcn_s_barrier();   // all reads done before combine overlay

    // flash combine across the s-split wave pair (overlay K/V ring)
    float* cmb = (float*)smem;      // per pair: 64 lanes x 96 f32 = 24KB
    float* myc = cmb + p * 6144 + lane * 96;
    if (ws == 1) {
        #pragma unroll
        for (int qg = 0; qg < 2; ++qg) {
            #pragma unroll
            for (int dh = 0; dh < 2; ++dh)
                #pragma unroll
                for (int v4 = 0; v4 < 4; ++v4)
                    *(f32x4*)(myc + (qg*2 + dh)*16 + v4*4) =
                        f32x4{oacc[qg][dh][v4*4+0], oacc[qg][dh][v4*4+1],
                              oacc[qg][dh][v4*4+2], oacc[qg][dh][v4*4+3]};
            #pragma unroll
            for (int v4 = 0; v4 < 4; ++v4)
                *(f32x4*)(myc + 64 + qg*16 + v4*4) =
                    f32x4{osum[qg][v4*4+0], osum[qg][v4*4+1],
                          osum[qg][v4*4+2], osum[qg][v4*4+3]};
        }
    }
    asm volatile("s_waitcnt lgkmcnt(0)" ::: "memory");
    __builtin_amdgcn_s_barrier();
    if (ws == 0) {
        #pragma unroll
        for (int qg = 0; qg < 2; ++qg) {
            #pragma unroll
            for (int dh = 0; dh < 2; ++dh)
                #pragma unroll
                for (int r = 0; r < 16; ++r)
                    oacc[qg][dh][r] += myc[(qg*2 + dh)*16 + r];
            #pragma unroll
            for (int r = 0; r < 16; ++r)
                osum[qg][r] += myc[64 + qg*16 + r];
        }
        // O rows: t = qt0 + qg*32 + (reg&3) + 8*(reg>>2) + 4*hf; col d = dh*32+l31
        #pragma unroll
        for (int qg = 0; qg < 2; ++qg) {
            float inv[16];
            #pragma unroll
            for (int r = 0; r < 16; ++r) inv[r] = 1.0f / osum[qg][r];
            #pragma unroll
            for (int dh = 0; dh < 2; ++dh)
                #pragma unroll
                for (int g = 0; g < 4; ++g)
                    #pragma unroll
                    for (int r0 = 0; r0 < 4; ++r0) {
                        int t = qt0 + qg*32 + g*8 + hf*4 + r0;
                        ao16[((size_t)(b*TT + t))*DIM + head*HD + dh*32 + l31] =
                            f2bf(oacc[qg][dh][g*4 + r0] * inv[g*4 + r0]);
                    }
        }
    }
}

extern "C" void kernel_launch(void* const* d_in, const int* in_sizes, int n_in,
                              void* d_out, int out_size, void* d_ws, size_t ws_size,
                              hipStream_t stream)
{
    const float* x     = (const float*)d_in[0];   // [4,2048,512] f32
    const float* Wqkv  = (const float*)d_in[1];   // [512,1024]  f32
    const float* Wproj = (const float*)d_in[2];   // [512,512]   f32
    const float* bproj = (const float*)d_in[3];   // [512]       f32
    float* out = (float*)d_out;                   // [4,2048,512] f32

    char* ws = (char*)d_ws;
    const size_t MB = 1024*1024;
    u16*   q16  = (u16*)(ws);                          // 8 MB  [b,h,t,d] bf16
    u16*   vt16 = (u16*)(ws + 8*MB);                   // 8 MB  [b,h,d,t] bf16
    u16*   ao16 = (u16*)(ws + 16*MB);                  // 8 MB  [b,t,dim] bf16
    u16*   x16  = (u16*)(ws + 24*MB);                  // 8 MB  [b,t,dim] bf16
    u16*   Wtq  = (u16*)(ws + 32*MB);                  // 1 MB  [1024][512]
    u16*   Wtp  = (u16*)(ws + 33*MB);                  // 0.5MB [512][512]
    float* qsq  = (float*)(ws + 34*MB);                // 256 KB (16B aligned)
    float* asq  = (float*)(ws + 34*MB + 262144);       // 128 B
    u32* bmaxsq = (u32*)(ws + 34*MB + 262144 + 128);   // 16 B

    (void)in_sizes; (void)n_in; (void)out_size; (void)ws_size;

    hipMemsetAsync(ws + 34*MB + 262144, 0, 144, stream);

    prep_kernel<<<1024, 256, 0, stream>>>(x, x16, bmaxsq, Wqkv, Wtq, Wproj, Wtp);

    qkv_mfma<<<64*8, 256, 0, stream>>>(x16, Wtq, q16, vt16);

    qsq_kernel<<<BH*8, 256, 0, stream>>>(q16, qsq, asq);

    attn_kernel<<<BH*16, 256, 0, stream>>>(q16, vt16, qsq, asq, bmaxsq, ao16);

    proj_mfma<<<64*4, 256, 0, stream>>>(ao16, Wtp, bproj, out);
}